// Round 1
// 557.141 us; speedup vs baseline: 1.0164x; 1.0164x over previous
//
#include <hip/hip_runtime.h>
#include <hip/hip_bf16.h>

#define LRELU_ALPHA 0.2f

typedef __bf16 bf16x8 __attribute__((ext_vector_type(8)));
typedef __bf16 bf16x4 __attribute__((ext_vector_type(4)));
typedef float f32x4 __attribute__((ext_vector_type(4)));

__device__ __forceinline__ float waveReduceSum(float v) {
#pragma unroll
    for (int off = 32; off > 0; off >>= 1)
        v += __shfl_xor(v, off, 64);
    return v;
}

// vall[k] = sum_o a[o*320+k]*a2[o]  (k<320); ABf = bf16(a) (128x320 row-major)
__global__ void k_prep(const float* __restrict__ a, const float* __restrict__ a2,
                       float* __restrict__ vall, __hip_bfloat16* __restrict__ ABf) {
    int idx = blockIdx.x * 256 + threadIdx.x;
    if (idx < 128 * 320) ABf[idx] = __float2bfloat16(a[idx]);
    if (idx < 320) {
        float s = 0.f;
#pragma unroll 8
        for (int o = 0; o < 128; ++o) s += a[o * 320 + idx] * a2[o];
        vall[idx] = s;
    }
}

// one wave per node: s_src/s_dst dots; also writes bf16 copy of x (XBf)
__global__ void k_node_scores(const float* __restrict__ x, const float* __restrict__ vall,
                              float* __restrict__ s_src, float* __restrict__ s_dst,
                              __hip_bfloat16* __restrict__ XBf, int N) {
    int wid = (int)((blockIdx.x * (size_t)blockDim.x + threadIdx.x) >> 6);
    int lane = threadIdx.x & 63;
    if (wid >= N) return;
    const float* xp = x + (size_t)wid * 128;
    float x0 = xp[lane], x1 = xp[lane + 64];
    XBf[(size_t)wid * 128 + lane]      = __float2bfloat16(x0);
    XBf[(size_t)wid * 128 + 64 + lane] = __float2bfloat16(x1);
    float ps = x0 * vall[lane] + x1 * vall[lane + 64];
    float pd = x0 * vall[128 + lane] + x1 * vall[192 + lane];
    ps = waveReduceSum(ps);
    pd = waveReduceSum(pd);
    if (lane == 0) { s_src[wid] = ps; s_dst[wid] = pd; }
}

__global__ void k_count(const int* __restrict__ e1, int E1, const int* __restrict__ e2, int E2,
                        int* __restrict__ cnt) {
    int e = blockIdx.x * blockDim.x + threadIdx.x;
    if (e >= E1 + E2) return;
    int src = (e < E1) ? e1[e] : e2[e - E1];
    atomicAdd(&cnt[src], 1);
}

// hierarchical exclusive scan of cnt[N] -> start[N+1], cursor[N]
__global__ void k_scan1(const int* __restrict__ cnt, int* __restrict__ bsum, int N) {
    __shared__ int red[256];
    int t = threadIdx.x;
    int idx = blockIdx.x * 256 + t;
    red[t] = (idx < N) ? cnt[idx] : 0;
    __syncthreads();
    for (int off = 128; off > 0; off >>= 1) {
        if (t < off) red[t] += red[t + off];
        __syncthreads();
    }
    if (t == 0) bsum[blockIdx.x] = red[0];
}

__global__ void k_scan2(int* __restrict__ bsum, int nb) {
    __shared__ int tmp[256];
    int t = threadIdx.x;
    int v = (t < nb) ? bsum[t] : 0;
    tmp[t] = v;
    __syncthreads();
    for (int off = 1; off < 256; off <<= 1) {
        int add = (t >= off) ? tmp[t - off] : 0;
        __syncthreads();
        tmp[t] += add;
        __syncthreads();
    }
    if (t < nb) bsum[t] = tmp[t] - v;  // exclusive
}

__global__ void k_scan3(const int* __restrict__ cnt, const int* __restrict__ bsum,
                        int* __restrict__ start, int* __restrict__ cursor, int N, int E) {
    __shared__ int tmp[256];
    int t = threadIdx.x;
    int idx = blockIdx.x * 256 + t;
    int v = (idx < N) ? cnt[idx] : 0;
    tmp[t] = v;
    __syncthreads();
    for (int off = 1; off < 256; off <<= 1) {
        int add = (t >= off) ? tmp[t - off] : 0;
        __syncthreads();
        tmp[t] += add;
        __syncthreads();
    }
    if (idx < N) {
        int excl = tmp[t] - v + bsum[blockIdx.x];
        start[idx] = excl;
        cursor[idx] = excl;
    }
    if (blockIdx.x == 0 && t == 0) start[N] = E;
}

// bucket edges by src: se[p] = (dst, e)
__global__ void k_scatter(const int* __restrict__ e1, int E1, const int* __restrict__ e2, int E2,
                          int* __restrict__ cursor, int2* __restrict__ se) {
    int e = blockIdx.x * blockDim.x + threadIdx.x;
    if (e >= E1 + E2) return;
    int src, dst;
    if (e < E1) { src = e1[e]; dst = e1[E1 + e]; }
    else { int t = e - E1; src = e2[t]; dst = e2[E2 + t]; }
    int p = atomicAdd(&cursor[src], 1);
    se[p] = make_int2(dst, e);
}

// one wave per node, FUSED, group-parallel: 4 groups of 16 lanes, each group owns
// one edge per slot; 8 edges/iteration (2 slots). emb row = f32x4/lane (dwordx4),
// dst x row = bf16x8/lane. u/w accumulators are per-group partials over all dims;
// combined across groups once per node via shfl_xor(16/32). No per-edge broadcast.
__global__ void k_gather(const __hip_bfloat16* __restrict__ XBf,
                         const float* __restrict__ emb1, const float* __restrict__ emb2, int E1,
                         const int* __restrict__ start, const int2* __restrict__ se,
                         const float* __restrict__ vall,
                         const float* __restrict__ s_src, const float* __restrict__ s_dst,
                         __hip_bfloat16* __restrict__ G, float* __restrict__ sxf, int N) {
    int n = (int)((blockIdx.x * (size_t)blockDim.x + threadIdx.x) >> 6);
    int lane = threadIdx.x & 63;
    if (n >= N) return;
    n = __builtin_amdgcn_readfirstlane(n);
    int g = lane >> 4;   // group = edge slot within a 4-edge batch
    int t = lane & 15;   // lane within group
    int b = start[n], en = start[n + 1];
    float ssrc = s_src[n];
    // per-lane a_rel slice: dims 4t..4t+3
    f32x4 r4 = *reinterpret_cast<const f32x4*>(vall + 256 + 4 * t);
    f32x4 w4 = {0.f, 0.f, 0.f, 0.f};
    float u8[8] = {0.f, 0.f, 0.f, 0.f, 0.f, 0.f, 0.f, 0.f};
    float rs = 0.f;

    for (int p = b; p < en; p += 8) {
        int q0 = p + g;
        int q1 = p + 4 + g;
        int c0 = (q0 < en) ? q0 : en - 1;   // en > b here, so en-1 valid
        int c1 = (q1 < en) ? q1 : en - 1;
        int2 d0 = se[c0];
        int2 d1 = se[c1];
        const float* ep0 = (d0.y < E1) ? emb1 + (size_t)d0.y * 64 : emb2 + (size_t)(d0.y - E1) * 64;
        const float* ep1 = (d1.y < E1) ? emb1 + (size_t)d1.y * 64 : emb2 + (size_t)(d1.y - E1) * 64;
        f32x4 em0 = *reinterpret_cast<const f32x4*>(ep0 + 4 * t);
        f32x4 em1 = *reinterpret_cast<const f32x4*>(ep1 + 4 * t);
        bf16x8 xv0 = *reinterpret_cast<const bf16x8*>(XBf + (size_t)d0.x * 128 + 8 * t);
        bf16x8 xv1 = *reinterpret_cast<const bf16x8*>(XBf + (size_t)d1.x * 128 + 8 * t);
        float sd0 = s_dst[d0.x], sd1 = s_dst[d1.x];
        float t0 = em0.x * r4.x + em0.y * r4.y + em0.z * r4.z + em0.w * r4.w;
        float t1 = em1.x * r4.x + em1.y * r4.y + em1.z * r4.z + em1.w * r4.w;
#pragma unroll
        for (int off = 1; off <= 8; off <<= 1) {
            t0 += __shfl_xor(t0, off, 64);
            t1 += __shfl_xor(t1, off, 64);
        }
        float sc0 = ssrc + sd0 + t0;
        float sc1 = ssrc + sd1 + t1;
        float pz0 = sc0 > 0.f ? sc0 : LRELU_ALPHA * sc0;
        float pz1 = sc1 > 0.f ? sc1 : LRELU_ALPHA * sc1;
        float e0 = __expf(-pz0);
        float e1v = __expf(-pz1);
        if (q0 >= en) e0 = 0.f;
        if (q1 >= en) e1v = 0.f;
        rs += e0 + e1v;
        w4 += e0 * em0 + e1v * em1;
#pragma unroll
        for (int j = 0; j < 8; ++j)
            u8[j] += e0 * (float)xv0[j] + e1v * (float)xv1[j];
    }

    // combine the 4 per-group partials (once per node)
#pragma unroll
    for (int j = 0; j < 8; ++j) {
        u8[j] += __shfl_xor(u8[j], 16, 64);
        u8[j] += __shfl_xor(u8[j], 32, 64);
    }
#pragma unroll
    for (int j = 0; j < 4; ++j) {
        w4[j] += __shfl_xor(w4[j], 16, 64);
        w4[j] += __shfl_xor(w4[j], 32, 64);
    }
    rs += __shfl_xor(rs, 16, 64);
    rs += __shfl_xor(rs, 32, 64);

    float inv = (rs == 0.f) ? 0.f : 1.f / rs;
    if (lane < 16) {
        __hip_bfloat16* gp = G + (size_t)n * 192;
        bf16x8 uu;
#pragma unroll
        for (int j = 0; j < 8; ++j) uu[j] = (__bf16)(u8[j] * inv);
        *reinterpret_cast<bf16x8*>(gp + 8 * lane) = uu;
        bf16x4 ww;
#pragma unroll
        for (int j = 0; j < 4; ++j) ww[j] = (__bf16)(w4[j] * inv);
        *reinterpret_cast<bf16x4*>(gp + 128 + 4 * lane) = ww;
        if (lane == 0) sxf[n] = (rs == 0.f) ? 0.f : 1.f;
    }
}

// out[n][o] = elu( sxf[n] * (x[n].a_src[o] + G[n].[a_dst|a_rel][o]) ) via bf16 MFMA.
__global__ __launch_bounds__(256) void k_mfma(
    const __hip_bfloat16* __restrict__ XBf, const __hip_bfloat16* __restrict__ G,
    const __hip_bfloat16* __restrict__ ABf, const float* __restrict__ sxf,
    float* __restrict__ out, int N) {
    int lane = threadIdx.x & 63;
    int wave = threadIdx.x >> 6;
    int m0 = blockIdx.x * 64 + wave * 16;
    int q = lane >> 4, m = lane & 15;
    int rowm = m0 + m; if (rowm >= N) rowm = N - 1;  // clamp; garbage rows never stored
    const __hip_bfloat16* xr = XBf + (size_t)rowm * 128 + q * 8;
    const __hip_bfloat16* gr = G + (size_t)rowm * 192 + q * 8;
    const __hip_bfloat16* br = ABf + (size_t)m * 320 + q * 8;
    f32x4 acc[8];
#pragma unroll
    for (int c = 0; c < 8; ++c) acc[c] = f32x4{0.f, 0.f, 0.f, 0.f};

#pragma unroll
    for (int s = 0; s < 4; ++s) {  // k = s*32 .. +32 from XBf
        bf16x8 af = *reinterpret_cast<const bf16x8*>(xr + s * 32);
#pragma unroll
        for (int c = 0; c < 8; ++c) {
            bf16x8 bf = *reinterpret_cast<const bf16x8*>(br + (size_t)c * 16 * 320 + s * 32);
            acc[c] = __builtin_amdgcn_mfma_f32_16x16x32_bf16(af, bf, acc[c], 0, 0, 0);
        }
    }
#pragma unroll
    for (int s = 0; s < 6; ++s) {  // k = 128 + s*32 .. +32 from G
        bf16x8 af = *reinterpret_cast<const bf16x8*>(gr + s * 32);
#pragma unroll
        for (int c = 0; c < 8; ++c) {
            bf16x8 bf = *reinterpret_cast<const bf16x8*>(br + (size_t)c * 16 * 320 + 128 + s * 32);
            acc[c] = __builtin_amdgcn_mfma_f32_16x16x32_bf16(af, bf, acc[c], 0, 0, 0);
        }
    }

    float sxr[4];
#pragma unroll
    for (int r = 0; r < 4; ++r) {
        int n = m0 + q * 4 + r;
        sxr[r] = (n < N) ? sxf[n] : 0.f;
    }
#pragma unroll
    for (int c = 0; c < 8; ++c) {
#pragma unroll
        for (int r = 0; r < 4; ++r) {
            int n = m0 + q * 4 + r;
            if (n < N) {
                float h = acc[c][r] * sxr[r];
                out[(size_t)n * 128 + c * 16 + m] = h > 0.f ? h : __expf(h) - 1.f;
            }
        }
    }
}

extern "C" void kernel_launch(void* const* d_in, const int* in_sizes, int n_in,
                              void* d_out, int out_size, void* d_ws, size_t ws_size,
                              hipStream_t stream) {
    const float* x    = (const float*)d_in[0];
    const int*   e1   = (const int*)d_in[1];
    const float* emb1 = (const float*)d_in[2];
    const int*   e2   = (const int*)d_in[3];
    const float* emb2 = (const float*)d_in[4];
    const float* a    = (const float*)d_in[5];
    const float* a2   = (const float*)d_in[6];
    float* out = (float*)d_out;

    const int N  = in_sizes[0] / 128;
    const int E1 = in_sizes[1] / 2;
    const int E2 = in_sizes[3] / 2;
    const int E  = E1 + E2;
    const int NB = (N + 255) / 256;  // <=256 (N<=65536)

    // workspace layout
    float* ws    = (float*)d_ws;
    float* vall  = ws;                                   // 512 f
    __hip_bfloat16* ABf = (__hip_bfloat16*)(ws + 512);   // 128*320 bf16 = 20480 f
    float* s_src = ws + 512 + 20480;                     // N
    float* s_dst = s_src + N;                            // N
    float* sxf   = s_dst + N;                            // N
    int*   cnt    = (int*)(sxf + N);                     // N
    int*   bsum   = cnt + N;                             // 256
    int*   start  = bsum + 256;                          // N+1
    int*   cursor = start + N + 1;                       // N+1
    size_t so = (size_t)((char*)(cursor + N + 1) - (char*)d_ws);
    so = (so + 15) & ~(size_t)15;
    int2*  se = (int2*)((char*)d_ws + so);               // E int2
    size_t xo = so + (size_t)E * sizeof(int2);
    xo = (xo + 15) & ~(size_t)15;
    __hip_bfloat16* XBf = (__hip_bfloat16*)((char*)d_ws + xo);  // N*128 bf16
    size_t go = xo + (size_t)N * 128 * sizeof(__hip_bfloat16);
    go = (go + 15) & ~(size_t)15;
    __hip_bfloat16* G = (__hip_bfloat16*)((char*)d_ws + go);    // N*192 bf16

    size_t needed = go + (size_t)N * 192 * sizeof(__hip_bfloat16);
    if (ws_size < needed) return;  // defensive

    hipMemsetAsync(cnt, 0, (size_t)N * sizeof(int), stream);

    k_prep<<<(128 * 320 + 255) / 256, 256, 0, stream>>>(a, a2, vall, ABf);
    k_node_scores<<<(N * 64 + 255) / 256, 256, 0, stream>>>(x, vall, s_src, s_dst, XBf, N);
    k_count<<<(E + 255) / 256, 256, 0, stream>>>(e1, E1, e2, E2, cnt);
    k_scan1<<<NB, 256, 0, stream>>>(cnt, bsum, N);
    k_scan2<<<1, 256, 0, stream>>>(bsum, NB);
    k_scan3<<<NB, 256, 0, stream>>>(cnt, bsum, start, cursor, N, E);
    k_scatter<<<(E + 255) / 256, 256, 0, stream>>>(e1, E1, e2, E2, cursor, se);
    k_gather<<<(N * 64 + 255) / 256, 256, 0, stream>>>(
        XBf, emb1, emb2, E1, start, se, vall, s_src, s_dst, G, sxf, N);
    k_mfma<<<(N + 63) / 64, 256, 0, stream>>>(XBf, G, ABf, sxf, out, N);
}